// Round 3
// baseline (334.367 us; speedup 1.0000x reference)
//
#include <hip/hip_runtime.h>

// Spline2D fused single-pass kernel: every output byte written exactly once.
// Block = 256 threads covers 16 rows (4096 floats) of one image; each thread
// stores 4x float4 (64 B). Patch-intersection test is block-uniform (scalar
// branch): ~65% of blocks run a pure zero-fill path at fill-kernel rates.
//
// out[b,R,C] = sum_{i,j} wx[i]*wy[j]*coeffs[(R-R0)+2+i, (C-C0)+2+j]
// for (R-R0),(C-C0) in [0,64], else 0, where R0=floor(x[b])+96, C0=floor(y[b])+96.

#define CW 72   // coeffs leading dim (64 + 2*4)

__global__ __launch_bounds__(256) void spline2d_fused(
    const float* __restrict__ coeffs,
    const float* __restrict__ x,
    const float* __restrict__ y,
    float* __restrict__ out)
{
    const int blk    = blockIdx.x;
    const int b      = blk >> 4;       // image index (block-uniform)
    const int seg    = blk & 15;       // 16-row segment within image
    const int Rstart = seg << 4;

    const float xv = x[b];             // block-uniform -> scalar load
    const float yv = y[b];
    const float fx = floorf(xv), fy = floorf(yv);
    const int   px = (int)fx,    py = (int)fy;
    const int   R0 = px + 96;          // patch top row in output
    const int   C0 = py + 96;          // patch left col in output

    const int t         = threadIdx.x;
    const int rowInPass = t >> 6;        // 0..3 (wave-uniform)
    const int col4      = (t & 63) << 2; // 0,4,...,252

    float* __restrict__ obase =
        out + ((size_t)b << 16) + ((size_t)Rstart << 8);

    const float4 z4 = make_float4(0.f, 0.f, 0.f, 0.f);

    // Block-uniform: does this 16-row segment intersect patch rows [R0, R0+64]?
    if (R0 > Rstart + 15 || R0 + 64 < Rstart) {
        // pure streaming zero path: 4 coalesced 16B stores, no VALU work
#pragma unroll
        for (int u = 0; u < 4; ++u) {
            *reinterpret_cast<float4*>(obase + (u << 10) + (rowInPass << 8) + col4) = z4;
        }
        return;
    }

    // slow path: compute spline weights (uniform per block)
    const float sx = xv - fx, sy = yv - fy;
    float wx[4], wy[4];
    {
        const float p = sx, p2 = p * p, p3 = p2 * p, q = 1.0f - p;
        wx[0] = p3 * (1.0f / 6.0f);
        wx[1] = -0.5f * p3 + 0.5f * p2 + 0.5f * p + (1.0f / 6.0f);
        wx[2] = 0.5f * p3 - p2 + (2.0f / 3.0f);
        wx[3] = q * q * q * (1.0f / 6.0f);
    }
    {
        const float p = sy, p2 = p * p, p3 = p2 * p, q = 1.0f - p;
        wy[0] = p3 * (1.0f / 6.0f);
        wy[1] = -0.5f * p3 + 0.5f * p2 + 0.5f * p + (1.0f / 6.0f);
        wy[2] = 0.5f * p3 - p2 + (2.0f / 3.0f);
        wy[3] = q * q * q * (1.0f / 6.0f);
    }

#pragma unroll
    for (int u = 0; u < 4; ++u) {
        const int R = Rstart + (u << 2) + rowInPass;
        const int r = R - R0;                 // patch row
        float4 v = z4;
        if ((unsigned)r <= 64u) {
            const int cb = col4 - C0;         // patch col of element 0
            float vv[4];
#pragma unroll
            for (int e = 0; e < 4; ++e) {
                const int c = cb + e;
                float s = 0.0f;
                if ((unsigned)c <= 64u) {
                    const float* p0 = coeffs + (r + 2) * CW + (c + 2);
#pragma unroll
                    for (int i = 0; i < 4; ++i) {
                        const float* row = p0 + i * CW;
                        const float rs = row[0] * wy[0] + row[1] * wy[1] +
                                         row[2] * wy[2] + row[3] * wy[3];
                        s = fmaf(wx[i], rs, s);
                    }
                }
                vv[e] = s;
            }
            v = make_float4(vv[0], vv[1], vv[2], vv[3]);
        }
        *reinterpret_cast<float4*>(obase + (u << 10) + (rowInPass << 8) + col4) = v;
    }
}

extern "C" void kernel_launch(void* const* d_in, const int* in_sizes, int n_in,
                              void* d_out, int out_size, void* d_ws, size_t ws_size,
                              hipStream_t stream) {
    const float* coeffs = (const float*)d_in[0];  // (72,72)
    const float* x      = (const float*)d_in[1];  // (1024,)
    const float* y      = (const float*)d_in[2];  // (1024,)
    float* out = (float*)d_out;                   // (1024,1,256,256)

    const int batch = in_sizes[1];                // 1024
    // 16 blocks per image, each covering 16 rows (4096 floats, 64 B/thread)
    spline2d_fused<<<batch * 16, 256, 0, stream>>>(coeffs, x, y, out);
}

// Round 4
// 259.024 us; speedup vs baseline: 1.2909x; 1.2909x over previous
//
#include <hip/hip_runtime.h>

// Spline2D fused single-pass kernel, v2: every output byte written exactly once.
// Block = 256 threads covers 16 rows (4096 floats) of one image.
// Fast path (block-uniform test, ~65% of blocks): pure 4x float4 zero stores.
// Slow path: separable spline blend staged in LDS --
//   step1: rb[slot][k]  = sum_i wx[i]*coeffs[r+2+i][k+2]   (1088 elems, 4 loads each)
//   step2: tmpl[slot][col] = sum_j wy[j]*rb[slot][c+j] or 0 (branch-free full rows)
//   store: 4x aligned float4 LDS reads + 4x float4 global stores (same as fast path)
// This removes R3's ~256 global loads/thread in patch blocks (the regression cause).

#define CW 72   // coeffs leading dim (64 + 2*4)

__global__ __launch_bounds__(256) void spline2d_fused2(
    const float* __restrict__ coeffs,
    const float* __restrict__ x,
    const float* __restrict__ y,
    float* __restrict__ out)
{
    __shared__ float rb[16][68];     // row-blended coeffs (4.25 KB)
    __shared__ float tmpl[16][256];  // full output rows for this segment (16 KB)

    const int blk    = blockIdx.x;
    const int b      = blk >> 4;     // image index (block-uniform)
    const int seg    = blk & 15;     // 16-row segment within image
    const int Rstart = seg << 4;

    const float xv = x[b];           // block-uniform -> scalar
    const float yv = y[b];
    const float fx = floorf(xv), fy = floorf(yv);
    const int   R0 = (int)fx + 96;   // patch top row in output
    const int   C0 = (int)fy + 96;   // patch left col in output

    const int t         = threadIdx.x;
    const int rowInPass = t >> 6;        // 0..3 (wave-uniform)
    const int col4      = (t & 63) << 2; // 0,4,...,252

    float* __restrict__ obase =
        out + ((size_t)b << 16) + ((size_t)Rstart << 8);
    const float4 z4 = make_float4(0.f, 0.f, 0.f, 0.f);

    // Block-uniform: does this 16-row segment intersect patch rows [R0, R0+64]?
    if (R0 > Rstart + 15 || R0 + 64 < Rstart) {
#pragma unroll
        for (int u = 0; u < 4; ++u) {
            *reinterpret_cast<float4*>(obase + (u << 10) + (rowInPass << 8) + col4) = z4;
        }
        return;
    }

    // ---- slow path: build the 16 output rows in LDS, then stream them out ----
    const float sx = xv - fx, sy = yv - fy;
    float wx[4], wy[4];
    {
        const float p = sx, p2 = p * p, p3 = p2 * p, q = 1.0f - p;
        wx[0] = p3 * (1.0f / 6.0f);
        wx[1] = -0.5f * p3 + 0.5f * p2 + 0.5f * p + (1.0f / 6.0f);
        wx[2] = 0.5f * p3 - p2 + (2.0f / 3.0f);
        wx[3] = q * q * q * (1.0f / 6.0f);
    }
    {
        const float p = sy, p2 = p * p, p3 = p2 * p, q = 1.0f - p;
        wy[0] = p3 * (1.0f / 6.0f);
        wy[1] = -0.5f * p3 + 0.5f * p2 + 0.5f * p + (1.0f / 6.0f);
        wy[2] = 0.5f * p3 - p2 + (2.0f / 3.0f);
        wy[3] = q * q * q * (1.0f / 6.0f);
    }

    // step1: row blend. slot = row within segment; r = patch row index.
    for (int idx = t; idx < 16 * 68; idx += 256) {
        const int slot = idx / 68;
        const int k    = idx - slot * 68;        // 0..67
        const int r    = Rstart + slot - R0;
        float v = 0.0f;
        if ((unsigned)r <= 64u) {
            const float* p0 = coeffs + (r + 2) * CW + (k + 2);
            v = p0[0] * wx[0] + p0[CW] * wx[1] + p0[2 * CW] * wx[2] + p0[3 * CW] * wx[3];
        }
        rb[slot][k] = v;
    }
    __syncthreads();

    // step2: col blend into full 256-wide rows (zeros outside patch cols).
    for (int k2 = t; k2 < 16 * 256; k2 += 256) {
        const int slot = k2 >> 8;
        const int col  = k2 & 255;
        const int r    = Rstart + slot - R0;
        const int c    = col - C0;               // patch col
        float v = 0.0f;
        if ((unsigned)r <= 64u && (unsigned)c <= 64u) {
            v = rb[slot][c] * wy[0] + rb[slot][c + 1] * wy[1] +
                rb[slot][c + 2] * wy[2] + rb[slot][c + 3] * wy[3];
        }
        tmpl[slot][col] = v;
    }
    __syncthreads();

    // store phase: identical shape to the fast path, values from LDS.
#pragma unroll
    for (int u = 0; u < 4; ++u) {
        const int slot = (u << 2) + rowInPass;
        const float4 v = *reinterpret_cast<const float4*>(&tmpl[slot][col4]);
        *reinterpret_cast<float4*>(obase + (u << 10) + (rowInPass << 8) + col4) = v;
    }
}

extern "C" void kernel_launch(void* const* d_in, const int* in_sizes, int n_in,
                              void* d_out, int out_size, void* d_ws, size_t ws_size,
                              hipStream_t stream) {
    const float* coeffs = (const float*)d_in[0];  // (72,72)
    const float* x      = (const float*)d_in[1];  // (1024,)
    const float* y      = (const float*)d_in[2];  // (1024,)
    float* out = (float*)d_out;                   // (1024,1,256,256)

    const int batch = in_sizes[1];                // 1024
    spline2d_fused2<<<batch * 16, 256, 0, stream>>>(coeffs, x, y, out);
}